// Round 7
// baseline (177.883 us; speedup 1.0000x reference)
//
#include <hip/hip_runtime.h>
#include <hip/hip_bf16.h>
#include <cstdint>
#include <cstddef>

#define BDIM 64
#define SDIM 512
#define HDIM 1024
#define MTOT (BDIM * SDIM)  // 32768

typedef __attribute__((ext_vector_type(8))) short short8;
typedef __attribute__((ext_vector_type(4))) float f32x4;

__device__ __forceinline__ unsigned int cvt2(float a, float b) {
  unsigned int r;
  asm("v_cvt_pk_bf16_f32 %0, %1, %2" : "=v"(r) : "v"(a), "v"(b));
  return r;
}

__device__ __forceinline__ void gld_lds16(const void* g, void* l) {
  __builtin_amdgcn_global_load_lds(
      (const __attribute__((address_space(1))) unsigned int*)g,
      (__attribute__((address_space(3))) unsigned int*)l, 16, 0, 0);
}

// tanh via hw exp2 + rcp: tanh(x) = 1 - 2/(e^{2x}+1). |err| ~1e-6, correct sat.
__device__ __forceinline__ float fast_tanh(float x) {
  const float e = __builtin_exp2f(x * 2.88539008f);  // 2*log2(e)
  return 1.0f - 2.0f * __builtin_amdgcn_rcpf(e + 1.0f);
}

// ---- W2 -> bf16, tile-major + XOR-swizzled (proven r2-r6) ----
__global__ __launch_bounds__(256) void prep_w2_kernel(const float* __restrict__ W,
                                                      char* __restrict__ w2s) {
  const int n = blockIdx.x * 2 + (threadIdx.x >> 7);
  const int g = threadIdx.x & 127;
  const int kt = g >> 3, gi = g & 7;
  const float* src = W + (size_t)n * 2048 + 1024 + g * 8;
  const float4 f0 = *reinterpret_cast<const float4*>(src);
  const float4 f1 = *reinterpret_cast<const float4*>(src + 4);
  uint4 u = make_uint4(cvt2(f0.x, f0.y), cvt2(f0.z, f0.w),
                       cvt2(f1.x, f1.y), cvt2(f1.z, f1.w));
  const int nblk = n >> 7, row = n & 127;
  const size_t off = ((size_t)(nblk * 16 + kt) * 128 + row) * 128 +
                     (size_t)(gi ^ (row & 7)) * 16;
  *reinterpret_cast<uint4*>(w2s + off) = u;
}

// ---- enc f32 -> bf16 tiled+swizzled, streaming layout (row-linear reads) ----
// Thread t handles cols [4t, 4t+3] of one row per iter: kt = t>>4,
// granule gi = (t>>1)&7, 8B half = (t&1)*8. Reads 1KB/wave coalesced.
__global__ __launch_bounds__(256) void prep_enc_kernel(const float* __restrict__ enc,
                                                       char* __restrict__ enc16) {
  const int tid = threadIdx.x;
  const int kt = tid >> 4;
  const int gi = (tid >> 1) & 7;
  const int half = (tid & 1) * 8;
  const int row_base = blockIdx.x * 16;
#pragma unroll 4
  for (int i = 0; i < 16; ++i) {
    const int grow = row_base + i;
    const float4 f = *reinterpret_cast<const float4*>(enc + (size_t)grow * 1024 + tid * 4);
    const uint2 u = make_uint2(cvt2(f.x, f.y), cvt2(f.z, f.w));
    const int strip = grow >> 7, rr = grow & 127;
    char* dst = enc16 + ((size_t)(strip * 16 + kt) * 16384) + rr * 128 +
                ((gi ^ (rr & 7)) * 16) + half;
    *reinterpret_cast<uint2*>(dst) = u;
  }
}

// ---- A[b,h] = hidden.W1 + bias; 4 independent FMA chains ----
__global__ __launch_bounds__(256) void compute_a_kernel(const float* __restrict__ hidden,
                                                        const float* __restrict__ W,
                                                        const float* __restrict__ bias,
                                                        float* __restrict__ A) {
  const int hc = blockIdx.x;  // 0..3
  const int b  = blockIdx.y;  // 0..63
  const int t  = threadIdx.x;
  __shared__ float hl[HDIM];
  *reinterpret_cast<float4*>(&hl[t * 4]) =
      *reinterpret_cast<const float4*>(hidden + (size_t)b * HDIM + t * 4);
  __syncthreads();
  const int h = hc * 256 + t;
  const float* wr = W + (size_t)h * 2048;
  float a0 = 0.f, a1 = 0.f, a2 = 0.f, a3 = 0.f;
  for (int k = 0; k < HDIM; k += 16) {
    const float4 w0 = *reinterpret_cast<const float4*>(wr + k);
    const float4 w1 = *reinterpret_cast<const float4*>(wr + k + 4);
    const float4 w2 = *reinterpret_cast<const float4*>(wr + k + 8);
    const float4 w3 = *reinterpret_cast<const float4*>(wr + k + 12);
    a0 += w0.x * hl[k]      + w0.y * hl[k + 1]  + w0.z * hl[k + 2]  + w0.w * hl[k + 3];
    a1 += w1.x * hl[k + 4]  + w1.y * hl[k + 5]  + w1.z * hl[k + 6]  + w1.w * hl[k + 7];
    a2 += w2.x * hl[k + 8]  + w2.y * hl[k + 9]  + w2.z * hl[k + 10] + w2.w * hl[k + 11];
    a3 += w3.x * hl[k + 12] + w3.y * hl[k + 13] + w3.z * hl[k + 14] + w3.w * hl[k + 15];
  }
  A[(size_t)b * HDIM + h] = bias[h] + ((a0 + a1) + (a2 + a3));
}

// ---- main GEMM (r5-proven): 256x256 tile, 8 waves, BK=64, dbuf, pure-DMA,
//      4 MFMA phases/K-tile with per-phase prefetch ----
__global__ __launch_bounds__(512, 2) void gemm8_kernel(const char* __restrict__ enc16,
                                                       const char* __restrict__ w2s,
                                                       const float* __restrict__ A,
                                                       const float* __restrict__ v,
                                                       float* __restrict__ sp) {
  __shared__ __align__(16) unsigned short As[2][2][128][64];  // 64 KB
  __shared__ __align__(16) unsigned short Bs[2][2][128][64];  // 64 KB
  __shared__ float red4[4][256];                              // 4 KB

  const int bid = blockIdx.x;
  const int lg = (bid & 7) * 64 + (bid >> 3);  // XCD swizzle, 512 % 8 == 0
  const int nblk = lg & 3, mstrip = lg >> 2;
  const int m0 = mstrip * 256, n0 = nblk * 256;
  const int b = m0 >> 9;

  const int tid = threadIdx.x;
  const int w = tid >> 6, l = tid & 63;
  const int wm = w >> 2, wn = w & 3;  // 2 x 4 wave grid
  const int lr = l & 15, lk = l >> 4;

  f32x4 acc[8][4];
#pragma unroll
  for (int i = 0; i < 8; ++i)
#pragma unroll
    for (int j = 0; j < 4; ++j) acc[i][j] = (f32x4){0.f, 0.f, 0.f, 0.f};

  const char* aT0 = enc16 + (size_t)((mstrip * 2 + 0) * 16) * 16384;
  const char* aT1 = enc16 + (size_t)((mstrip * 2 + 1) * 16) * 16384;
  const char* bT0 = w2s + (size_t)((nblk * 2 + 0) * 16) * 16384;
  const char* bT1 = w2s + (size_t)((nblk * 2 + 1) * 16) * 16384;

  const int wbase = w * 1024;
  const int lofs = l * 16;

#define STAGE(srcp, dstp)                                                  \
  do {                                                                     \
    gld_lds16((const char*)(srcp) + wbase + lofs, (char*)(dstp) + wbase);  \
    gld_lds16((const char*)(srcp) + 8192 + wbase + lofs,                   \
              (char*)(dstp) + 8192 + wbase);                               \
  } while (0)

  // prologue: K-tile 0 into buffer 0
  STAGE(aT0, &As[0][0][0][0]);
  STAGE(aT1, &As[0][1][0][0]);
  STAGE(bT0, &Bs[0][0][0][0]);
  STAGE(bT1, &Bs[0][1][0][0]);

  const int gax = lr & 7;

  for (int kt = 0; kt < 16; ++kt) {
    const int cur = kt & 1, nxt = cur ^ 1;
    __syncthreads();  // tile kt resident (implicit vmcnt(0)+lgkmcnt(0) drain)
    const size_t ko = (size_t)(kt + 1) * 16384;
    const bool pf = (kt < 15);
    const char* Ah = (const char*)&As[cur][wm][0][0];
    const char* Bh = (const char*)&Bs[cur][wn >> 1][0][0];
    const int brow0 = (wn & 1) * 64;

    short8 af[4], bf[4];
#pragma unroll
    for (int ks = 0; ks < 2; ++ks) {
      const int gq = ((ks * 4 + lk) ^ gax) * 16;
#pragma unroll
      for (int mg = 0; mg < 2; ++mg) {
        if (pf) {
          const int ph = ks * 2 + mg;
          if (ph == 0)      STAGE(aT0 + ko, &As[nxt][0][0][0]);
          else if (ph == 1) STAGE(bT0 + ko, &Bs[nxt][0][0][0]);
          else if (ph == 2) STAGE(aT1 + ko, &As[nxt][1][0][0]);
          else              STAGE(bT1 + ko, &Bs[nxt][1][0][0]);
        }
        if (mg == 0) {
#pragma unroll
          for (int f = 0; f < 4; ++f)
            bf[f] = *reinterpret_cast<const short8*>(
                Bh + (brow0 + f * 16 + lr) * 128 + gq);
        }
#pragma unroll
        for (int f = 0; f < 4; ++f)
          af[f] = *reinterpret_cast<const short8*>(
              Ah + ((mg * 4 + f) * 16 + lr) * 128 + gq);
        asm volatile("s_waitcnt lgkmcnt(0)" ::: "memory");
        __builtin_amdgcn_sched_barrier(0);
        __builtin_amdgcn_s_setprio(1);
#pragma unroll
        for (int fm = 0; fm < 4; ++fm)
#pragma unroll
          for (int fn = 0; fn < 4; ++fn)
            acc[mg * 4 + fm][fn] = __builtin_amdgcn_mfma_f32_16x16x32_bf16(
                af[fm], bf[fn], acc[mg * 4 + fm][fn], 0, 0, 0);
        __builtin_amdgcn_s_setprio(0);
      }
    }
  }
#undef STAGE

  // ---- epilogue: partial[m] = sum_n v[n] * tanh(C[m,n] + A[b,n]) ----
  float a_n[4], v_n[4];
#pragma unroll
  for (int fn = 0; fn < 4; ++fn) {
    const int n = wn * 64 + fn * 16 + lr;
    a_n[fn] = A[(size_t)b * HDIM + n0 + n];
    v_n[fn] = v[n0 + n];
  }
#pragma unroll
  for (int fm8 = 0; fm8 < 8; ++fm8) {
#pragma unroll
    for (int r = 0; r < 4; ++r) {
      float s = 0.f;
#pragma unroll
      for (int fn = 0; fn < 4; ++fn)
        s += v_n[fn] * fast_tanh(acc[fm8][fn][r] + a_n[fn]);
      s += __shfl_xor(s, 1);
      s += __shfl_xor(s, 2);
      s += __shfl_xor(s, 4);
      s += __shfl_xor(s, 8);
      if (lr == 0) red4[wn][wm * 128 + fm8 * 16 + lk * 4 + r] = s;
    }
  }
  __syncthreads();
  if (tid < 256) {
    const float ssum = red4[0][tid] + red4[1][tid] + red4[2][tid] + red4[3][tid];
    sp[(size_t)nblk * MTOT + m0 + tid] = ssum;
  }
}

// ---- softmax over s (512) per b; sums 4 partials ----
__global__ __launch_bounds__(512) void softmax4_kernel(const float* __restrict__ sp,
                                                       float* __restrict__ wts) {
  const int b = blockIdx.x, s = threadIdx.x;
  float sc = 0.f;
#pragma unroll
  for (int j = 0; j < 4; ++j) sc += sp[(size_t)j * MTOT + b * SDIM + s];
  float m = sc;
#pragma unroll
  for (int d = 1; d < 64; d <<= 1) m = fmaxf(m, __shfl_xor(m, d));
  __shared__ float redm[8], reds[8];
  if ((s & 63) == 0) redm[s >> 6] = m;
  __syncthreads();
  m = redm[0];
#pragma unroll
  for (int j = 1; j < 8; ++j) m = fmaxf(m, redm[j]);
  const float e = expf(sc - m);
  float sum = e;
#pragma unroll
  for (int d = 1; d < 64; d <<= 1) sum += __shfl_xor(sum, d);
  if ((s & 63) == 0) reds[s >> 6] = sum;
  __syncthreads();
  float tot = 0.f;
#pragma unroll
  for (int j = 0; j < 8; ++j) tot += reds[j];
  wts[(size_t)b * SDIM + s] = e / tot;
}

// ---- context[b,h] = sum_s w[b,s] * enc[b,s,h] (f32 enc, accuracy headroom) ----
__global__ __launch_bounds__(256) void context_kernel(const float* __restrict__ enc,
                                                      const float* __restrict__ wts,
                                                      float* __restrict__ ctx) {
  const int hc = blockIdx.x;
  const int b  = blockIdx.y;
  const int t  = threadIdx.x;
  __shared__ float wl[SDIM];
  wl[t] = wts[(size_t)b * SDIM + t];
  wl[t + 256] = wts[(size_t)b * SDIM + 256 + t];
  __syncthreads();
  const int h = hc * 256 + t;
  const float* e0 = enc + (size_t)b * SDIM * HDIM + h;
  float acc0 = 0.f, acc1 = 0.f;
  for (int s = 0; s < SDIM; s += 2) {
    acc0 += wl[s] * e0[(size_t)s * HDIM];
    acc1 += wl[s + 1] * e0[(size_t)(s + 1) * HDIM];
  }
  ctx[(size_t)b * HDIM + h] = acc0 + acc1;
}

// ================== fallback path (small ws): r6-proven fused-convert GEMM ==================
__global__ __launch_bounds__(512, 2) void gemm8f_kernel(const float* __restrict__ enc,
                                                        const char* __restrict__ w2s,
                                                        const float* __restrict__ A,
                                                        const float* __restrict__ v,
                                                        float* __restrict__ sp) {
  __shared__ __align__(16) unsigned short As[2][2][128][64];
  __shared__ __align__(16) unsigned short Bs[2][2][128][64];
  __shared__ float red4[4][256];

  const int bid = blockIdx.x;
  const int lg = (bid & 7) * 64 + (bid >> 3);
  const int nblk = lg & 3, mstrip = lg >> 2;
  const int m0 = mstrip * 256, n0 = nblk * 256;
  const int b = m0 >> 9;
  const int tid = threadIdx.x;
  const int w = tid >> 6, l = tid & 63;
  const int wm = w >> 2, wn = w & 3;
  const int lr = l & 15, lk = l >> 4;

  f32x4 acc[8][4];
#pragma unroll
  for (int i = 0; i < 8; ++i)
#pragma unroll
    for (int j = 0; j < 4; ++j) acc[i][j] = (f32x4){0.f, 0.f, 0.f, 0.f};

  const int row0 = tid >> 3, g0 = tid & 7;
  const float* encA = enc + (size_t)m0 * HDIM + g0 * 8;
  const char* bT0 = w2s + (size_t)((nblk * 2 + 0) * 16) * 16384;
  const char* bT1 = w2s + (size_t)((nblk * 2 + 1) * 16) * 16384;
  const int wbase = w * 1024;
  const int lofs = l * 16;

#define STAGE_B(srcp, dstp)                                                \
  do {                                                                     \
    gld_lds16((const char*)(srcp) + wbase + lofs, (char*)(dstp) + wbase);  \
    gld_lds16((const char*)(srcp) + 8192 + wbase + lofs,                   \
              (char*)(dstp) + 8192 + wbase);                               \
  } while (0)
#define LOAD_A(pfv, ii, ktv)                                                 \
  do {                                                                      \
    const float* s_ = encA + (size_t)(row0 + (ii) * 64) * HDIM + (ktv) * 64; \
    pfv[2 * (ii)]     = *reinterpret_cast<const float4*>(s_);               \
    pfv[2 * (ii) + 1] = *reinterpret_cast<const float4*>(s_ + 4);           \
  } while (0)

  float4 pf[8];
  LOAD_A(pf, 0, 0); LOAD_A(pf, 1, 0); LOAD_A(pf, 2, 0); LOAD_A(pf, 3, 0);
  STAGE_B(bT0, &Bs[0][0][0][0]);
  STAGE_B(bT1, &Bs[0][1][0][0]);

  const int gax = lr & 7;

  for (int kt = 0; kt < 16; ++kt) {
    const int cur = kt & 1, nxt = cur ^ 1;
#pragma unroll
    for (int i = 0; i < 4; ++i) {
      const int row = row0 + i * 64;
      uint4 u = make_uint4(cvt2(pf[2 * i].x, pf[2 * i].y),
                           cvt2(pf[2 * i].z, pf[2 * i].w),
                           cvt2(pf[2 * i + 1].x, pf[2 * i + 1].y),
                           cvt2(pf[2 * i + 1].z, pf[2 * i + 1].w));
      char* dst = reinterpret_cast<char*>(&As[cur][row >> 7][0][0]);
      *reinterpret_cast<uint4*>(dst + (row & 127) * 128 + ((g0 ^ (row & 7)) * 16)) = u;
    }
    __syncthreads();

    const bool pfb = (kt < 15);
    const char* Ah = (const char*)&As[cur][wm][0][0];
    const char* Bh = (const char*)&Bs[cur][wn >> 1][0][0];
    const int brow0 = (wn & 1) * 64;

    short8 af[4], bf[4];
#pragma unroll
    for (int ks = 0; ks < 2; ++ks) {
      const int gq = ((ks * 4 + lk) ^ gax) * 16;
#pragma unroll
      for (int mg = 0; mg < 2; ++mg) {
        if (pfb) {
          const int ph = ks * 2 + mg;
          if (ph == 0)      { LOAD_A(pf, 0, kt + 1); LOAD_A(pf, 1, kt + 1); }
          else if (ph == 1) { LOAD_A(pf, 2, kt + 1); LOAD_A(pf, 3, kt + 1); }
          else if (ph == 2) { STAGE_B(bT0 + (size_t)(kt + 1) * 16384, &Bs[nxt][0][0][0]); }
          else              { STAGE_B(bT1 + (size_t)(kt + 1) * 16384, &Bs[nxt][1][0][0]); }
        }
        if (mg == 0) {
#pragma unroll
          for (int f = 0; f < 4; ++f)
            bf[f] = *reinterpret_cast<const short8*>(
                Bh + (brow0 + f * 16 + lr) * 128 + gq);
        }
#pragma unroll
        for (int f = 0; f < 4; ++f)
          af[f] = *reinterpret_cast<const short8*>(
              Ah + ((mg * 4 + f) * 16 + lr) * 128 + gq);
        asm volatile("s_waitcnt lgkmcnt(0)" ::: "memory");
        __builtin_amdgcn_sched_barrier(0);
        __builtin_amdgcn_s_setprio(1);
#pragma unroll
        for (int fm = 0; fm < 4; ++fm)
#pragma unroll
          for (int fn = 0; fn < 4; ++fn)
            acc[mg * 4 + fm][fn] = __builtin_amdgcn_mfma_f32_16x16x32_bf16(
                af[fm], bf[fn], acc[mg * 4 + fm][fn], 0, 0, 0);
        __builtin_amdgcn_s_setprio(0);
      }
    }
  }
#undef STAGE_B
#undef LOAD_A

  float a_n[4], v_n[4];
#pragma unroll
  for (int fn = 0; fn < 4; ++fn) {
    const int n = wn * 64 + fn * 16 + lr;
    a_n[fn] = A[(size_t)b * HDIM + n0 + n];
    v_n[fn] = v[n0 + n];
  }
#pragma unroll
  for (int fm8 = 0; fm8 < 8; ++fm8) {
#pragma unroll
    for (int r = 0; r < 4; ++r) {
      float s = 0.f;
#pragma unroll
      for (int fn = 0; fn < 4; ++fn)
        s += v_n[fn] * fast_tanh(acc[fm8][fn][r] + a_n[fn]);
      s += __shfl_xor(s, 1);
      s += __shfl_xor(s, 2);
      s += __shfl_xor(s, 4);
      s += __shfl_xor(s, 8);
      if (lr == 0) red4[wn][wm * 128 + fm8 * 16 + lk * 4 + r] = s;
    }
  }
  __syncthreads();
  if (tid < 256) {
    const float ssum = red4[0][tid] + red4[1][tid] + red4[2][tid] + red4[3][tid];
    sp[(size_t)nblk * MTOT + m0 + tid] = ssum;
  }
}

extern "C" void kernel_launch(void* const* d_in, const int* in_sizes, int n_in,
                              void* d_out, int out_size, void* d_ws, size_t ws_size,
                              hipStream_t stream) {
  const float* hidden = (const float*)d_in[0];
  const float* enc    = (const float*)d_in[1];
  const float* W      = (const float*)d_in[2];
  const float* bias   = (const float*)d_in[3];
  const float* v      = (const float*)d_in[4];

  float* ctx = (float*)d_out;                // [64*1024] context
  float* wts = (float*)d_out + BDIM * HDIM;  // [64*512] attention weights

  char* ws = (char*)d_ws;
  const size_t ENC16_BYTES = (size_t)64 * 1024 * 1024;
  const size_t BIG_NEED = ENC16_BYTES + 2 * 1024 * 1024 + 256 * 1024 + 512 * 1024;

  if (ws_size >= BIG_NEED) {
    char* enc16 = ws;
    char* w2s   = ws + ENC16_BYTES;
    float* A    = (float*)(ws + ENC16_BYTES + 2 * 1024 * 1024);
    float* sp   = (float*)(ws + ENC16_BYTES + 2 * 1024 * 1024 + 256 * 1024);
    hipLaunchKernelGGL(prep_w2_kernel, dim3(512), dim3(256), 0, stream, W, w2s);
    hipLaunchKernelGGL(compute_a_kernel, dim3(4, 64), dim3(256), 0, stream, hidden, W, bias, A);
    hipLaunchKernelGGL(prep_enc_kernel, dim3(2048), dim3(256), 0, stream, enc, enc16);
    hipLaunchKernelGGL(gemm8_kernel, dim3(512), dim3(512), 0, stream, enc16, w2s, A, v, sp);
    hipLaunchKernelGGL(softmax4_kernel, dim3(64), dim3(512), 0, stream, sp, wts);
    hipLaunchKernelGGL(context_kernel, dim3(4, 64), dim3(256), 0, stream, enc, wts, ctx);
  } else {
    char* w2s = ws;
    float* A  = (float*)(ws + (size_t)2 * 1024 * 1024);
    float* sp = (float*)(ws + (size_t)2 * 1024 * 1024 + 256 * 1024);
    hipLaunchKernelGGL(prep_w2_kernel, dim3(512), dim3(256), 0, stream, W, w2s);
    hipLaunchKernelGGL(compute_a_kernel, dim3(4, 64), dim3(256), 0, stream, hidden, W, bias, A);
    hipLaunchKernelGGL(gemm8f_kernel, dim3(512), dim3(512), 0, stream, enc, w2s, A, v, sp);
    hipLaunchKernelGGL(softmax4_kernel, dim3(64), dim3(512), 0, stream, sp, wts);
    hipLaunchKernelGGL(context_kernel, dim3(4, 64), dim3(256), 0, stream, enc, wts, ctx);
  }
}